// Round 1
// baseline (60.423 us; speedup 1.0000x reference)
//
#include <hip/hip_runtime.h>

typedef __bf16 bf16x8 __attribute__((ext_vector_type(8)));
typedef float  f32x16 __attribute__((ext_vector_type(16)));

static_assert(sizeof(bf16x8) == 16, "bf16x8 must be 16B");

#define MFMA32(A, B, C) __builtin_amdgcn_mfma_f32_32x32x16_bf16((A), (B), (C), 0, 0, 0)

__device__ __forceinline__ bf16x8 load8_bf(const float* __restrict__ p, float scale) {
    const float4 a = *reinterpret_cast<const float4*>(p);
    const float4 b = *reinterpret_cast<const float4*>(p + 4);
    bf16x8 r;
    r[0] = (__bf16)(a.x * scale); r[1] = (__bf16)(a.y * scale);
    r[2] = (__bf16)(a.z * scale); r[3] = (__bf16)(a.w * scale);
    r[4] = (__bf16)(b.x * scale); r[5] = (__bf16)(b.y * scale);
    r[6] = (__bf16)(b.z * scale); r[7] = (__bf16)(b.w * scale);
    return r;
}

__device__ __forceinline__ unsigned short f2bf(float f) {
    return __builtin_bit_cast(unsigned short, (__bf16)f);
}

__device__ __forceinline__ f32x16 zero16() {
    f32x16 z;
#pragma unroll
    for (int e = 0; e < 16; ++e) z[e] = 0.f;
    return z;
}

// Output element mapping for v_mfma_f32_32x32x16_bf16 C/D (verified m74/m101):
// col = lane&31, row = (reg&3) + 8*(reg>>2) + 4*(lane>>5)

__global__ __launch_bounds__(256) void attn32(
    const float* __restrict__ x,
    const float* __restrict__ Wk, const float* __restrict__ bk,
    const float* __restrict__ Wq, const float* __restrict__ bq,
    const float* __restrict__ Wv, const float* __restrict__ bv,
    const float* __restrict__ Wp, const float* __restrict__ bp,
    float* __restrict__ out, int Btot)
{
    // per-wave LDS slice: 7680 B
    //  [0,2560)    Q bf16 [32][40]   (stride 80 B)
    //  [2560,5120) K bf16 [32][40]
    //  [5120,7680) V bf16 [32][40]
    //  S  f32 [32][36] overlays [0,4608) after Q/K fragment reads
    //  Y  bf16 [32][40] overlays [0,2560) after S reads
    __shared__ float4 lds4[4][480];

    const int lane = threadIdx.x & 63;
    const int wave = threadIdx.x >> 6;
    const int col  = lane & 31;   // C-layout col / A-layout row
    const int hi   = lane >> 5;

    char* const base = (char*)lds4[wave];
    unsigned short* const qk16 = (unsigned short*)base;
    unsigned short* const v16  = (unsigned short*)(base + 5120);

    const float RS32 = 0.17677669529663687f;  // 1/sqrt(32)

    // ---- per-wave weight B-fragments: B[k][c] = W[c][k]; lane needs W[col][hi*8 + 0..7] (+16) ----
    const int wrow = col * 32 + hi * 8;
    const bf16x8 wk0 = load8_bf(Wk + wrow, 1.f), wk1 = load8_bf(Wk + wrow + 16, 1.f);
    const bf16x8 wq0 = load8_bf(Wq + wrow, RS32), wq1 = load8_bf(Wq + wrow + 16, RS32); // fold 1/sqrt(C)
    const bf16x8 wv0 = load8_bf(Wv + wrow, 1.f), wv1 = load8_bf(Wv + wrow + 16, 1.f);
    const bf16x8 wp0 = load8_bf(Wp + wrow, 1.f), wp1 = load8_bf(Wp + wrow + 16, 1.f);
    const float bkv = bk[col];
    const float bqv = bq[col] * RS32;
    const float bvv = bv[col];
    const float bpv = bp[col];

    const int gw = blockIdx.x * (blockDim.x >> 6) + wave;
    const int nw = gridDim.x * (blockDim.x >> 6);

    for (int b = gw; b < Btot; b += nw) {
        const float* xb = x + (size_t)b * 1024;

        // X A-fragments: A[row=col][k = hi*8 + j] (+16 for second MFMA)
        const bf16x8 xa0 = load8_bf(xb + col * 32 + hi * 8, 1.f);
        const bf16x8 xa1 = load8_bf(xb + col * 32 + 16 + hi * 8, 1.f);

        f32x16 acc;

        // ---- K = X*Wk^T + bk ----
        acc = zero16();
        acc = MFMA32(xa0, wk0, acc);
        acc = MFMA32(xa1, wk1, acc);
#pragma unroll
        for (int e = 0; e < 16; ++e) {
            const int r = (e & 3) + 8 * (e >> 2) + 4 * hi;
            qk16[1280 + r * 40 + col] = f2bf(acc[e] + bkv);
        }
        // ---- Q = (X*Wq^T + bq) / sqrt(C)  (scale pre-folded) ----
        acc = zero16();
        acc = MFMA32(xa0, wq0, acc);
        acc = MFMA32(xa1, wq1, acc);
#pragma unroll
        for (int e = 0; e < 16; ++e) {
            const int r = (e & 3) + 8 * (e >> 2) + 4 * hi;
            qk16[r * 40 + col] = f2bf(acc[e] + bqv);
        }
        // ---- V = X*Wv^T + bv ----
        acc = zero16();
        acc = MFMA32(xa0, wv0, acc);
        acc = MFMA32(xa1, wv1, acc);
#pragma unroll
        for (int e = 0; e < 16; ++e) {
            const int r = (e & 3) + 8 * (e >> 2) + 4 * hi;
            v16[r * 40 + col] = f2bf(acc[e] + bvv);
        }

        asm volatile("" ::: "memory");  // LDS writes above ordered before reads below

        // ---- S = Q * K^T : A from Q rows, B[k=c][j] = K[j][c] -> K rows; identical addressing ----
        const bf16x8 qa0 = *(const bf16x8*)(base + col * 80 + hi * 16);
        const bf16x8 qa1 = *(const bf16x8*)(base + col * 80 + 32 + hi * 16);
        const bf16x8 kb0 = *(const bf16x8*)(base + 2560 + col * 80 + hi * 16);
        const bf16x8 kb1 = *(const bf16x8*)(base + 2560 + col * 80 + 32 + hi * 16);
        acc = zero16();
        acc = MFMA32(qa0, kb0, acc);
        acc = MFMA32(qa1, kb1, acc);

        // write S (fp32, [32][36]) -- data-dependent on K/Q reads, so ordering is safe
        float* const sf = (float*)base;
#pragma unroll
        for (int e = 0; e < 16; ++e) {
            const int r = (e & 3) + 8 * (e >> 2) + 4 * hi;
            sf[r * 36 + col] = acc[e];
        }

        asm volatile("" ::: "memory");  // S writes before S reads

        // ---- read S rows in A-layout; causal mask; softmax across lane pair {l, l^32} ----
        float sv[16];
        {
            const char* sb = base + col * 144 + hi * 32;
            *(float4*)&sv[0]  = *(const float4*)(sb);
            *(float4*)&sv[4]  = *(const float4*)(sb + 16);
            *(float4*)&sv[8]  = *(const float4*)(sb + 64);
            *(float4*)&sv[12] = *(const float4*)(sb + 80);
        }
        const int i = col;  // this lane's attention row
#pragma unroll
        for (int e = 0; e < 16; ++e) {
            const int j = (e < 8) ? (hi * 8 + e) : (16 + hi * 8 + (e - 8));
            if (j > i) sv[e] = -__builtin_inff();
        }
        float m = sv[0];
#pragma unroll
        for (int e = 1; e < 16; ++e) m = fmaxf(m, sv[e]);
        m = fmaxf(m, __shfl_xor(m, 32));
        float pe[16];
        float sum = 0.f;
#pragma unroll
        for (int e = 0; e < 16; ++e) { pe[e] = __expf(sv[e] - m); sum += pe[e]; }
        sum += __shfl_xor(sum, 32);
        const float inv = 1.f / sum;
        bf16x8 p0, p1;
#pragma unroll
        for (int e = 0; e < 8; ++e) {
            p0[e] = (__bf16)(pe[e] * inv);
            p1[e] = (__bf16)(pe[8 + e] * inv);
        }

        // ---- Y = att * V^T : B[k=t][j] = V[j][t] -> V rows ----
        const bf16x8 vb0 = *(const bf16x8*)(base + 5120 + col * 80 + hi * 16);
        const bf16x8 vb1 = *(const bf16x8*)(base + 5120 + col * 80 + 32 + hi * 16);
        acc = zero16();
        acc = MFMA32(p0, vb0, acc);
        acc = MFMA32(p1, vb1, acc);

        // Y -> LDS bf16 (overlays Q region; data-dependent on S reads)
#pragma unroll
        for (int e = 0; e < 16; ++e) {
            const int r = (e & 3) + 8 * (e >> 2) + 4 * hi;
            qk16[r * 40 + col] = f2bf(acc[e]);
        }

        asm volatile("" ::: "memory");  // Y writes before Y reads

        const bf16x8 ya0 = *(const bf16x8*)(base + col * 80 + hi * 16);
        const bf16x8 ya1 = *(const bf16x8*)(base + col * 80 + 32 + hi * 16);
        acc = zero16();
        acc = MFMA32(ya0, wp0, acc);
        acc = MFMA32(ya1, wp1, acc);

        // ---- store: out flat [T, B, C] : element i*2^20 + b*32 + c ----
        float* const ob = out + (size_t)b * 32 + col;
#pragma unroll
        for (int e = 0; e < 16; ++e) {
            const int r = (e & 3) + 8 * (e >> 2) + 4 * hi;
            ob[(size_t)r << 20] = acc[e] + bpv;
        }

        asm volatile("" ::: "memory");  // Y reads before next-iteration Q/K/V writes (WAR)
    }
}

extern "C" void kernel_launch(void* const* d_in, const int* in_sizes, int n_in,
                              void* d_out, int out_size, void* d_ws, size_t ws_size,
                              hipStream_t stream) {
    const float* x  = (const float*)d_in[0];
    const float* Wk = (const float*)d_in[1];
    const float* bk = (const float*)d_in[2];
    const float* Wq = (const float*)d_in[3];
    const float* bq = (const float*)d_in[4];
    const float* Wv = (const float*)d_in[5];
    const float* bv = (const float*)d_in[6];
    const float* Wp = (const float*)d_in[7];
    const float* bp = (const float*)d_in[8];
    float* out = (float*)d_out;

    const int Btot = in_sizes[0] / 1024;  // [B,32,32] fp32
    dim3 grid(2048), block(256);
    hipLaunchKernelGGL(attn32, grid, block, 0, stream,
                       x, Wk, bk, Wq, bq, Wv, bv, Wp, bp, out, Btot);
}

// Round 2
// 53.169 us; speedup vs baseline: 1.1364x; 1.1364x over previous
//
#include <hip/hip_runtime.h>

typedef __bf16 bf16x8 __attribute__((ext_vector_type(8)));
typedef float  f32x16 __attribute__((ext_vector_type(16)));
typedef unsigned int uint4v __attribute__((ext_vector_type(4)));

#define MFMA32(A, B, C) __builtin_amdgcn_mfma_f32_32x32x16_bf16((A), (B), (C), 0, 0, 0)

__device__ __forceinline__ bf16x8 load8_bf(const float* __restrict__ p, float scale) {
    const float4 a = *reinterpret_cast<const float4*>(p);
    const float4 b = *reinterpret_cast<const float4*>(p + 4);
    bf16x8 r;
    r[0] = (__bf16)(a.x * scale); r[1] = (__bf16)(a.y * scale);
    r[2] = (__bf16)(a.z * scale); r[3] = (__bf16)(a.w * scale);
    r[4] = (__bf16)(b.x * scale); r[5] = (__bf16)(b.y * scale);
    r[6] = (__bf16)(b.z * scale); r[7] = (__bf16)(b.w * scale);
    return r;
}

__device__ __forceinline__ unsigned pack2(float a, float b) {
    unsigned la = (unsigned)__builtin_bit_cast(unsigned short, (__bf16)a);
    unsigned lb = (unsigned)__builtin_bit_cast(unsigned short, (__bf16)b);
    return la | (lb << 16);
}

__device__ __forceinline__ void swap32(unsigned& a, unsigned& b) {
#if __has_builtin(__builtin_amdgcn_permlane32_swap)
    auto r = __builtin_amdgcn_permlane32_swap(a, b, false, false);
    a = r[0]; b = r[1];
#else
    asm("v_permlane32_swap_b32 %0, %1" : "+v"(a), "+v"(b));
#endif
}

// Input: lane holds M[col][r(e,hi)] for e=0..15 (C-layout of M^T, col=lane&31,
// r(e,hi)=(e&3)+8*(e>>2)+4*hi). Output: MFMA A/B fragments where lane holds
// M[lane&31][k]: f0 covers k=hi*8+q, f1 covers k=16+hi*8+q (q=0..7).
// Derivation: D[q]=pack(e=2q,e=2q+1) covers cols {base(q),base(q)+1}+4hi;
// permlane32_swap(D0,D2)->(w0,w2), (D1,D3)->(w1,w3), (D4,D6)/(D5,D7) for f1.
__device__ __forceinline__ void rearrange(const f32x16& a, bf16x8& f0, bf16x8& f1) {
    unsigned D0 = pack2(a[0], a[1]),   D1 = pack2(a[2], a[3]);
    unsigned D2 = pack2(a[4], a[5]),   D3 = pack2(a[6], a[7]);
    unsigned D4 = pack2(a[8], a[9]),   D5 = pack2(a[10], a[11]);
    unsigned D6 = pack2(a[12], a[13]), D7 = pack2(a[14], a[15]);
    swap32(D0, D2); swap32(D1, D3); swap32(D4, D6); swap32(D5, D7);
    f0 = __builtin_bit_cast(bf16x8, uint4v{D0, D1, D2, D3});
    f1 = __builtin_bit_cast(bf16x8, uint4v{D4, D5, D6, D7});
}

__device__ __forceinline__ void ld4(const float* __restrict__ p,
                                    float4& r0, float4& r1, float4& r2, float4& r3) {
    r0 = *reinterpret_cast<const float4*>(p);
    r1 = *reinterpret_cast<const float4*>(p + 4);
    r2 = *reinterpret_cast<const float4*>(p + 16);
    r3 = *reinterpret_cast<const float4*>(p + 20);
}

__device__ __forceinline__ void cvt8(const float4& a, const float4& b, bf16x8& f) {
    f[0] = (__bf16)a.x; f[1] = (__bf16)a.y; f[2] = (__bf16)a.z; f[3] = (__bf16)a.w;
    f[4] = (__bf16)b.x; f[5] = (__bf16)b.y; f[6] = (__bf16)b.z; f[7] = (__bf16)b.w;
}

// LDS-free causal self-attention for T=C=32, one wave per batch.
// All transposes in-register: compute K^T=Wk*X^T, Q^T=Wq*X^T, V^T=Wv*X^T,
// Y^T=V*P^T via MFMA operand order; C-layout -> fragment via pack+permlane32.
__global__ __launch_bounds__(256, 3) void attn32(
    const float* __restrict__ x,
    const float* __restrict__ Wk, const float* __restrict__ bk,
    const float* __restrict__ Wq, const float* __restrict__ bq,
    const float* __restrict__ Wv, const float* __restrict__ bv,
    const float* __restrict__ Wp, const float* __restrict__ bp,
    float* __restrict__ out, int Btot)
{
    const int lane = threadIdx.x & 63;
    const int col  = lane & 31;
    const int hi   = lane >> 5;

    // fold 1/sqrt(32) * log2(e) into Q so softmax uses exp2 directly
    const float SC = 0.17677669529663687f * 1.4426950408889634f;

    const int wrow = col * 32 + hi * 8;
    // weight fragments: lane holds W[col][hi*8+q] (+16) — serves as A or B frag
    const bf16x8 wk0 = load8_bf(Wk + wrow, 1.f), wk1 = load8_bf(Wk + wrow + 16, 1.f);
    const bf16x8 wq0 = load8_bf(Wq + wrow, SC),  wq1 = load8_bf(Wq + wrow + 16, SC);
    const bf16x8 wv0 = load8_bf(Wv + wrow, 1.f), wv1 = load8_bf(Wv + wrow + 16, 1.f);
    const bf16x8 wp0 = load8_bf(Wp + wrow, 1.f), wp1 = load8_bf(Wp + wrow + 16, 1.f);

    // transposed-compute biases are per-ELEMENT (row index r of the C tile)
    f32x16 bk16, bq16, bv16;
#pragma unroll
    for (int e = 0; e < 16; ++e) {
        const int r = (e & 3) + 8 * (e >> 2) + 4 * hi;
        bk16[e] = bk[r];
        bq16[e] = bq[r] * SC;
        bv16[e] = bv[r];
    }
    const float bpv = bp[col];  // final output is non-transposed: per-lane bias

    const int gw = blockIdx.x * 4 + (threadIdx.x >> 6);
    const int nw = gridDim.x * 4;

    float4 A0, A1, A2, A3;
    if (gw < Btot) ld4(x + (size_t)gw * 1024 + wrow, A0, A1, A2, A3);

    for (int b = gw; b < Btot; b += nw) {
        // consume prefetched x, then immediately issue next-batch loads
        bf16x8 xa0, xa1;
        cvt8(A0, A1, xa0);
        cvt8(A2, A3, xa1);
        const int nb = b + nw;
        if (nb < Btot) ld4(x + (size_t)nb * 1024 + wrow, A0, A1, A2, A3);

        f32x16 acc;

        // K^T = Wk * X^T (+bk per-element): lane holds K[col][r(e,hi)]
        acc = bk16;
        acc = MFMA32(wk0, xa0, acc);
        acc = MFMA32(wk1, xa1, acc);
        bf16x8 ka0, ka1; rearrange(acc, ka0, ka1);

        // Q^T (scale+log2e folded)
        acc = bq16;
        acc = MFMA32(wq0, xa0, acc);
        acc = MFMA32(wq1, xa1, acc);
        bf16x8 qb0, qb1; rearrange(acc, qb0, qb1);

        // V^T: lane holds V[col(time)][r(channel)]
        acc = bv16;
        acc = MFMA32(wv0, xa0, acc);
        acc = MFMA32(wv1, xa1, acc);
        bf16x8 vb0, vb1; rearrange(acc, vb0, vb1);

        // S^T = K * Q^T: lane (query row i=col) holds S'[i][j=r(e,hi)]
        f32x16 s;
#pragma unroll
        for (int e = 0; e < 16; ++e) s[e] = 0.f;
        s = MFMA32(ka0, qb0, s);
        s = MFMA32(ka1, qb1, s);

        // causal mask + softmax; row i spans lane pair {col, col+32}
        float sv[16];
        float m = -3.0e38f;
#pragma unroll
        for (int e = 0; e < 16; ++e) {
            const int j = (e & 3) + 8 * (e >> 2) + 4 * hi;
            sv[e] = (j <= col) ? s[e] : -__builtin_inff();
            m = fmaxf(m, sv[e]);
        }
        m = fmaxf(m, __shfl_xor(m, 32));
        float pe[16];
        float sum = 0.f;
#pragma unroll
        for (int e = 0; e < 16; ++e) { pe[e] = __builtin_amdgcn_exp2f(sv[e] - m); sum += pe[e]; }
        sum += __shfl_xor(sum, 32);
        const float inv = __builtin_amdgcn_rcpf(sum);
        f32x16 pv;
#pragma unroll
        for (int e = 0; e < 16; ++e) pv[e] = pe[e] * inv;
        bf16x8 pa0, pa1; rearrange(pv, pa0, pa1);

        // Y^T = V * P^T (contract v-channel against att-key-time, per reference)
        f32x16 yt;
#pragma unroll
        for (int e = 0; e < 16; ++e) yt[e] = 0.f;
        yt = MFMA32(vb0, pa0, yt);
        yt = MFMA32(vb1, pa1, yt);
        bf16x8 ya0, ya1; rearrange(yt, ya0, ya1);

        // out = Y * Wp^T + bp: C-layout row r = time i, col = out channel
        f32x16 o;
#pragma unroll
        for (int e = 0; e < 16; ++e) o[e] = bpv;
        o = MFMA32(ya0, wp0, o);
        o = MFMA32(ya1, wp1, o);

        // out flat [T, B, C]: element r*2^20 + b*32 + col; nontemporal to keep
        // the 134 MB write stream from evicting x out of L3
        float* ob = out + (size_t)b * 32 + col;
#pragma unroll
        for (int e = 0; e < 16; ++e) {
            const int r = (e & 3) + 8 * (e >> 2) + 4 * hi;
            __builtin_nontemporal_store(o[e], ob + ((size_t)r << 20));
        }
    }
}

extern "C" void kernel_launch(void* const* d_in, const int* in_sizes, int n_in,
                              void* d_out, int out_size, void* d_ws, size_t ws_size,
                              hipStream_t stream) {
    const float* x  = (const float*)d_in[0];
    const float* Wk = (const float*)d_in[1];
    const float* bk = (const float*)d_in[2];
    const float* Wq = (const float*)d_in[3];
    const float* bq = (const float*)d_in[4];
    const float* Wv = (const float*)d_in[5];
    const float* bv = (const float*)d_in[6];
    const float* Wp = (const float*)d_in[7];
    const float* bp = (const float*)d_in[8];
    float* out = (float*)d_out;

    const int Btot = in_sizes[0] / 1024;  // [B,32,32] fp32
    dim3 grid(2048), block(256);
    hipLaunchKernelGGL(attn32, grid, block, 0, stream,
                       x, Wk, bk, Wq, bq, Wv, bv, Wp, bp, out, Btot);
}